// Round 3
// baseline (88.855 us; speedup 1.0000x reference)
//
#include <hip/hip_runtime.h>

// opool: x [B, D*C, h, w], D=12. Per (b,c) group of 12 contiguous h*w maps,
// flat argmax over (D,h,w) -> winning orientation d; output that h*w map.
// Key simplification: flat argmax first-occurrence == smallest d whose
// per-map max equals the group max. So scan = pure per-map fmax reduce.
// B=8, C=64, h=w=128 -> 512 groups, 12 maps/group, 16384 floats/map.

constexpr int D_ORI  = 12;
constexpr int HW     = 128 * 128;           // 16384 floats per map
constexpr int GROUP  = D_ORI * HW;          // 196608 floats per group
constexpr int BLOCK  = 256;                 // 4 waves
constexpr int MAP_F4 = HW / 4;              // 4096 float4 per map
constexpr int PARTS  = 8;                   // copy slices per group
constexpr int SLICE_F4 = HW / PARTS / 4;    // 512 float4 per slice

// Kernel 1: one block per orientation map; pure max reduce (no index).
__global__ __launch_bounds__(BLOCK) void opool_mapmax(const float* __restrict__ x,
                                                      float* __restrict__ ws) {
    const int m = blockIdx.x;               // map id in [0, ngroups*12)
    const float4* __restrict__ p4 =
        reinterpret_cast<const float4*>(x) + (size_t)m * MAP_F4;
    const int tid = threadIdx.x;

    // 16 independent loads, 4 independent max accumulators (max MLP, no chain)
    float a0 = -__builtin_huge_valf(), a1 = a0, a2 = a0, a3 = a0;
    #pragma unroll
    for (int i = 0; i < 16; ++i) {
        float4 v = p4[tid + i * BLOCK];
        float mv = fmaxf(fmaxf(v.x, v.y), fmaxf(v.z, v.w));
        if ((i & 3) == 0) a0 = fmaxf(a0, mv);
        else if ((i & 3) == 1) a1 = fmaxf(a1, mv);
        else if ((i & 3) == 2) a2 = fmaxf(a2, mv);
        else a3 = fmaxf(a3, mv);
    }
    float a = fmaxf(fmaxf(a0, a1), fmaxf(a2, a3));

    #pragma unroll
    for (int off = 32; off >= 1; off >>= 1)
        a = fmaxf(a, __shfl_xor(a, off, 64));

    __shared__ float s[BLOCK / 64];
    const int wave = tid >> 6;
    if ((tid & 63) == 0) s[wave] = a;
    __syncthreads();
    if (tid == 0) {
        #pragma unroll
        for (int i = 1; i < BLOCK / 64; ++i) a = fmaxf(a, s[i]);
        ws[m] = a;
    }
}

// Kernel 2: per (group, slice): pick d = first argmax over 12 map-maxes
// (L2-hot, 48 B broadcast), copy 1/8 of the winning map.
__global__ __launch_bounds__(BLOCK) void opool_copy(const float* __restrict__ x,
                                                    const float* __restrict__ ws,
                                                    float* __restrict__ out) {
    const int g = blockIdx.x / PARTS;
    const int j = blockIdx.x % PARTS;

    const float* __restrict__ wm = ws + (size_t)g * D_ORI;
    float M = wm[0]; int d = 0;
    #pragma unroll
    for (int i = 1; i < D_ORI; ++i) {
        float v = wm[i];
        if (v > M) { M = v; d = i; }        // strict >: first-d tie-break
    }

    const float4* __restrict__ src =
        reinterpret_cast<const float4*>(x + (size_t)g * GROUP + (size_t)d * HW)
        + (size_t)j * SLICE_F4;
    float4* __restrict__ dst =
        reinterpret_cast<float4*>(out + (size_t)g * HW) + (size_t)j * SLICE_F4;

    const int tid = threadIdx.x;
    #pragma unroll
    for (int k = 0; k < SLICE_F4 / BLOCK; ++k)
        dst[tid + k * BLOCK] = src[tid + k * BLOCK];
}

extern "C" void kernel_launch(void* const* d_in, const int* in_sizes, int n_in,
                              void* d_out, int out_size, void* d_ws, size_t ws_size,
                              hipStream_t stream) {
    const float* x = (const float*)d_in[0];
    float* out     = (float*)d_out;
    float* ws      = (float*)d_ws;
    const int ngroups = in_sizes[0] / GROUP;            // 512

    opool_mapmax<<<ngroups * D_ORI, BLOCK, 0, stream>>>(x, ws);
    opool_copy<<<ngroups * PARTS, BLOCK, 0, stream>>>(x, ws, out);
}

// Round 4
// 71.226 us; speedup vs baseline: 1.2475x; 1.2475x over previous
//
#include <hip/hip_runtime.h>

// opool: x [B, D*C, h, w], D=12. Per (b,c) group of 12 contiguous 128x128 maps,
// output the map with the largest element (first-d tie-break == flat argmax
// first-occurrence). Fused single-pass: scan maps in order, keep the current
// winner's per-thread fragment in registers -> no winner re-read.
// Traffic: 402.7 MB read + 33.6 MB write (vs 470 MB in two-pass).

typedef float f32x4 __attribute__((ext_vector_type(4)));

constexpr int D_ORI  = 12;
constexpr int HW     = 128 * 128;       // 16384 floats per map
constexpr int MAP_F4 = HW / 4;          // 4096 float4 per map
constexpr int GROUP  = D_ORI * HW;      // 196608 floats per group
constexpr int BLOCK  = 1024;            // 16 waves; thread owns 4 float4/map
constexpr int NW     = BLOCK / 64;      // 16 waves

__device__ __forceinline__ float vmax16(f32x4 a, f32x4 b, f32x4 c, f32x4 d) {
    float m0 = fmaxf(fmaxf(a.x, a.y), fmaxf(a.z, a.w));
    float m1 = fmaxf(fmaxf(b.x, b.y), fmaxf(b.z, b.w));
    float m2 = fmaxf(fmaxf(c.x, c.y), fmaxf(c.z, c.w));
    float m3 = fmaxf(fmaxf(d.x, d.y), fmaxf(d.z, d.w));
    return fmaxf(fmaxf(m0, m1), fmaxf(m2, m3));
}

__global__ __launch_bounds__(BLOCK) void opool_fused(const float* __restrict__ x,
                                                     float* __restrict__ out) {
    const int g = blockIdx.x;
    const f32x4* __restrict__ base =
        reinterpret_cast<const f32x4*>(x) + (size_t)g * (D_ORI * MAP_F4);
    const int tid  = threadIdx.x;
    const int wave = tid >> 6;
    const int lane = tid & 63;

    __shared__ float sred[D_ORI][NW];   // per-d slots: no WAR across iterations

    f32x4 v0, v1, v2, v3;               // current map fragment
    f32x4 w0, w1, w2, w3;               // prefetched next map fragment
    f32x4 k0, k1, k2, k3;               // kept (winning) fragment
    float best = -__builtin_huge_valf();

    {   // load map 0
        const f32x4* p = base + tid;
        v0 = __builtin_nontemporal_load(p);
        v1 = __builtin_nontemporal_load(p + BLOCK);
        v2 = __builtin_nontemporal_load(p + 2 * BLOCK);
        v3 = __builtin_nontemporal_load(p + 3 * BLOCK);
    }
    k0 = v0; k1 = v1; k2 = v2; k3 = v3;

    #pragma unroll
    for (int d = 0; d < D_ORI; ++d) {
        // issue next map's loads BEFORE the reduce; the lgkm-only barrier
        // below leaves them in flight (no vmcnt drain -> no HBM bubble)
        if (d + 1 < D_ORI) {
            const f32x4* p = base + (size_t)(d + 1) * MAP_F4 + tid;
            w0 = __builtin_nontemporal_load(p);
            w1 = __builtin_nontemporal_load(p + BLOCK);
            w2 = __builtin_nontemporal_load(p + 2 * BLOCK);
            w3 = __builtin_nontemporal_load(p + 3 * BLOCK);
        }

        float mv = vmax16(v0, v1, v2, v3);
        #pragma unroll
        for (int off = 32; off >= 1; off >>= 1)
            mv = fmaxf(mv, __shfl_xor(mv, off, 64));
        if (lane == 0) sred[d][wave] = mv;
        asm volatile("s_waitcnt lgkmcnt(0)" ::: "memory");
        __builtin_amdgcn_s_barrier();
        asm volatile("" ::: "memory");

        float gm = sred[d][0];
        #pragma unroll
        for (int i = 1; i < NW; ++i) gm = fmaxf(gm, sred[d][i]);

        if (gm > best) {                // block-uniform; strict > = first-d tie-break
            best = gm;
            k0 = v0; k1 = v1; k2 = v2; k3 = v3;
        }
        if (d + 1 < D_ORI) { v0 = w0; v1 = w1; v2 = w2; v3 = w3; }
    }

    f32x4* o = reinterpret_cast<f32x4*>(out) + (size_t)g * MAP_F4 + tid;
    __builtin_nontemporal_store(k0, o);
    __builtin_nontemporal_store(k1, o + BLOCK);
    __builtin_nontemporal_store(k2, o + 2 * BLOCK);
    __builtin_nontemporal_store(k3, o + 3 * BLOCK);
}

extern "C" void kernel_launch(void* const* d_in, const int* in_sizes, int n_in,
                              void* d_out, int out_size, void* d_ws, size_t ws_size,
                              hipStream_t stream) {
    const float* x = (const float*)d_in[0];
    float* out     = (float*)d_out;
    const int ngroups = in_sizes[0] / GROUP;   // 512
    opool_fused<<<ngroups, BLOCK, 0, stream>>>(x, out);
}